// Round 1
// baseline (1998.970 us; speedup 1.0000x reference)
//
#include <hip/hip_runtime.h>

#define DD 256
#define TT 32
#define BB 8
#define BETA_ 0.8f

// ---- workspace layout (float offsets) ----
#define OFF_COEF   0                        // 256: [0]=lam [1]=beta^2 lam^2, [8+t]=f_t, [64+n]=(1-lam)^n
#define OFF_PSI_R  256                      // 256 x 256 (row i, col = t0*8+b)
#define OFF_PSI_I  (OFF_PSI_R + 65536)
#define OFF_P_R    (OFF_PSI_I + 65536)      // P1..P4 (Uh^2,4,8,16), 4 x 65536
#define OFF_P_I    (OFF_P_R + 262144)
#define OFF_PHI_R  (OFF_P_I + 262144)       // 256 x 8192 (col = a*256 + t0*8 + b)
#define OFF_PHI_I  (OFF_PHI_R + 2097152)
#define OFF_XI_R   (OFF_PHI_I + 2097152)    // 256 x 8192
#define OFF_XI_I   (OFF_XI_R + 2097152)
#define OFF_H_R    (OFF_XI_I + 2097152)     // 32 x (256 k x 256 i), H_c = conj(m) Uh^c
#define OFF_H_I    (OFF_H_R + 2097152)
#define OFF_PACC   (OFF_H_I + 2097152)      // 32 x 8 x 256 probs accumulator
#define WS_FLOATS  (OFF_PACC + 65536)

// ---------------- scalar coefficients ----------------
__global__ void k_coef(const float* __restrict__ Lam, float* __restrict__ ws)
{
    if (threadIdx.x != 0) return;
    float lam = 1.f / (1.f + expf(-Lam[0]));
    float oml = 1.f - lam;
    ws[OFF_COEF + 0] = lam;
    ws[OFF_COEF + 1] = BETA_ * BETA_ * lam * lam;
    float w = 1.f;
    for (int n = 0; n < 64; ++n) { ws[OFF_COEF + 64 + n] = w; w *= oml; }
    // identity-component recurrence (exactly mirrors the scan on the I/D coefficient)
    float a1 = 1.f / 256.f, a2 = 1.f / 256.f;
    for (int t = 0; t < 32; ++t) {
        a1 = oml * a1;                                   // layer-1 carry id-coef
        float y1 = BETA_ * a1 + (1.f - BETA_) / 256.f;   // layer-1 emit id-coef
        a2 = lam * y1 + oml * a2;                        // layer-2 carry id-coef
        ws[OFF_COEF + 8 + t] = BETA_ * a2 + (1.f - BETA_) / 256.f; // final emit id-coef
    }
}

// ---------------- H_0 = conj(normalized K rows), layout [k][i] ----------------
__global__ __launch_bounds__(256) void k_norm(const float* __restrict__ Kr,
                                              const float* __restrict__ Ki,
                                              float* __restrict__ ws)
{
    int k = blockIdx.x, i = threadIdx.x;
    float vr = Kr[k * 256 + i], vi = Ki[k * 256 + i];
    __shared__ float red[256];
    red[i] = vr * vr + vi * vi;
    __syncthreads();
    for (int s = 128; s > 0; s >>= 1) { if (i < s) red[i] += red[i + s]; __syncthreads(); }
    float inv = 1.f / sqrtf(red[0]);
    ws[OFF_H_R + (long)k * 256 + i] =  vr * inv;
    ws[OFF_H_I + (long)k * 256 + i] = -vi * inv;   // conj
}

// ---------------- pure states psi (kron of 3 modalities), col = t0*8+b ----------------
__global__ __launch_bounds__(256) void k_psi(
    const float* __restrict__ xt, const float* __restrict__ xa, const float* __restrict__ xv,
    const float* __restrict__ sm,
    const float* __restrict__ Wt, const float* __restrict__ bt,
    const float* __restrict__ Wa, const float* __restrict__ ba,
    const float* __restrict__ Wv, const float* __restrict__ bv,
    const float* __restrict__ Pt, const float* __restrict__ Pa, const float* __restrict__ Pv,
    float* __restrict__ ws)
{
    const int colS = blockIdx.x;            // t0*8 + b
    const int t0 = colS >> 3, b = colS & 7;
    const long bt_ = (long)b * TT + t0;     // (B,T) flattened
    const int tid = threadIdx.x;
    __shared__ float rt[4], ra[8], rv[8], inv3[3];
    if (tid < 4) {
        float acc = bt[tid];
        const float* x = xt + bt_ * 300;
        for (int q = 0; q < 300; ++q) acc = fmaf(x[q], Wt[q * 4 + tid], acc);
        rt[tid] = fmaxf(acc, 0.f);
    } else if (tid < 12) {
        int u = tid - 4;
        float acc = ba[u];
        const float* x = xa + bt_ * 74;
        for (int q = 0; q < 74; ++q) acc = fmaf(x[q], Wa[q * 8 + u], acc);
        ra[u] = fmaxf(acc, 0.f);
    } else if (tid < 20) {
        int u = tid - 12;
        float acc = bv[u];
        const float* x = xv + bt_ * 35;
        for (int q = 0; q < 35; ++q) acc = fmaf(x[q], Wv[q * 8 + u], acc);
        rv[u] = fmaxf(acc, 0.f);
    }
    __syncthreads();
    if (tid == 0) {
        float s = 0.f; for (int u = 0; u < 4; ++u) s += rt[u] * rt[u];
        inv3[0] = 1.f / fmaxf(sqrtf(s), 1e-12f);
        s = 0.f; for (int u = 0; u < 8; ++u) s += ra[u] * ra[u];
        inv3[1] = 1.f / fmaxf(sqrtf(s), 1e-12f);
        s = 0.f; for (int u = 0; u < 8; ++u) s += rv[u] * rv[u];
        inv3[2] = 1.f / fmaxf(sqrtf(s), 1e-12f);
    }
    __syncthreads();
    float s0 = sm[bt_ * 2], s1 = sm[bt_ * 2 + 1];
    int spk = (s1 > s0) ? 1 : 0;            // argmax (first-max on tie)
    int d = tid;                             // psi index: d = ti*64 + ai*8 + vi
    int ti = d >> 6, ai = (d >> 3) & 7, vi = d & 7;
    float amp = (rt[ti] * inv3[0]) * (ra[ai] * inv3[1]) * (rv[vi] * inv3[2]);
    float ph = Pt[spk * 4 + ti] + Pa[spk * 8 + ai] + Pv[spk * 8 + vi];
    ws[OFF_PSI_R + (long)d * 256 + colS] = amp * cosf(ph);
    ws[OFF_PSI_I + (long)d * 256 + colS] = amp * sinf(ph);
}

// ---------------- complex GEMM: C[m][col] = sum_i A[m][i]*B[i][col], M=K=256 ----------------
// batched via blockIdx.z with element strides aS/bS/cS applied to both planes.
__global__ __launch_bounds__(256) void k_cgemm(
    const float* __restrict__ Ar, const float* __restrict__ Ai,
    const float* __restrict__ Br, const float* __restrict__ Bi,
    float* __restrict__ Cr, float* __restrict__ Ci,
    int N, int ldB, int ldC, long aS, long bS, long cS)
{
    const long bz = blockIdx.z;
    Ar += bz * aS; Ai += bz * aS;
    Br += bz * bS; Bi += bz * bS;
    Cr += bz * cS; Ci += bz * cS;
    const int col0 = blockIdx.x * 64, row0 = blockIdx.y * 64;
    __shared__ __align__(16) float As_r[16][68], As_i[16][68], Bs_r[16][68], Bs_i[16][68];
    const int tid = threadIdx.x;
    const int tx = tid & 15, ty = tid >> 4;
    float accr[4][4] = {}; float acci[4][4] = {};
    for (int k0 = 0; k0 < 256; k0 += 16) {
        const int li = tid & 15, lm = tid >> 4;
#pragma unroll
        for (int p = 0; p < 4; ++p) {
            int m = lm + p * 16;
            As_r[li][m] = Ar[(long)(row0 + m) * 256 + k0 + li];
            As_i[li][m] = Ai[(long)(row0 + m) * 256 + k0 + li];
        }
        const int lc = tid & 63, lk = tid >> 6;
#pragma unroll
        for (int p = 0; p < 4; ++p) {
            int kk = lk + p * 4;
            int c = col0 + lc;
            float vr = 0.f, vi = 0.f;
            if (c < N) {
                vr = Br[(long)(k0 + kk) * ldB + c];
                vi = Bi[(long)(k0 + kk) * ldB + c];
            }
            Bs_r[kk][lc] = vr; Bs_i[kk][lc] = vi;
        }
        __syncthreads();
#pragma unroll
        for (int kk = 0; kk < 16; ++kk) {
            float4 a4r = *(const float4*)(&As_r[kk][ty * 4]);
            float4 a4i = *(const float4*)(&As_i[kk][ty * 4]);
            float4 b4r = *(const float4*)(&Bs_r[kk][tx * 4]);
            float4 b4i = *(const float4*)(&Bs_i[kk][tx * 4]);
            float ar_[4] = {a4r.x, a4r.y, a4r.z, a4r.w};
            float ai_[4] = {a4i.x, a4i.y, a4i.z, a4i.w};
            float br_[4] = {b4r.x, b4r.y, b4r.z, b4r.w};
            float bi_[4] = {b4i.x, b4i.y, b4i.z, b4i.w};
#pragma unroll
            for (int i = 0; i < 4; ++i)
#pragma unroll
                for (int j = 0; j < 4; ++j) {
                    accr[i][j] = fmaf(ar_[i], br_[j], accr[i][j]);
                    accr[i][j] = fmaf(-ai_[i], bi_[j], accr[i][j]);
                    acci[i][j] = fmaf(ar_[i], bi_[j], acci[i][j]);
                    acci[i][j] = fmaf(ai_[i], br_[j], acci[i][j]);
                }
        }
        __syncthreads();
    }
#pragma unroll
    for (int i = 0; i < 4; ++i)
#pragma unroll
        for (int j = 0; j < 4; ++j) {
            int c = col0 + tx * 4 + j;
            if (c < N) {
                Cr[(long)(row0 + ty * 4 + i) * ldC + c] = accr[i][j];
                Ci[(long)(row0 + ty * 4 + i) * ldC + c] = acci[i][j];
            }
        }
}

// ---------------- fused measurement: A = H_c * Xi(group j0), probs += w*|A|^2 ----------------
// grid: x = kblk*4 + colchunk (16), y = j0 (32), z = c (32)
__global__ __launch_bounds__(256) void k_measure(float* __restrict__ ws)
{
    const int c  = blockIdx.z;
    const int j0 = blockIdx.y;
    if (j0 + c > 31) return;
    const int kblk  = blockIdx.x >> 2;
    const int chunk = blockIdx.x & 3;
    const int ncols = 8 * (j0 + 1);
    const int col0 = chunk * 64;
    if (col0 >= ncols) return;
    const float* Hr = ws + OFF_H_R + (long)c * 65536;
    const float* Hi = ws + OFF_H_I + (long)c * 65536;
    const float* Xr = ws + OFF_XI_R;
    const float* Xi = ws + OFF_XI_I;
    float* pacc = ws + OFF_PACC;
    const int row0 = kblk * 64;
    __shared__ __align__(16) float As_r[16][68], As_i[16][68], Bs_r[16][68], Bs_i[16][68];
    __shared__ float part[64][9];
    __shared__ float wt_s[64];
    const int tid = threadIdx.x;
    if (tid < 64) wt_s[tid] = ws[OFF_COEF + 64 + tid];
    for (int e = tid; e < 64 * 9; e += 256) (&part[0][0])[e] = 0.f;
    const int tx = tid & 15, ty = tid >> 4;
    float accr[4][4] = {}; float acci[4][4] = {};
    for (int k0 = 0; k0 < 256; k0 += 16) {
        const int li = tid & 15, lm = tid >> 4;
#pragma unroll
        for (int p = 0; p < 4; ++p) {
            int m = lm + p * 16;
            As_r[li][m] = Hr[(long)(row0 + m) * 256 + k0 + li];
            As_i[li][m] = Hi[(long)(row0 + m) * 256 + k0 + li];
        }
        const int lc = tid & 63, lk = tid >> 6;
#pragma unroll
        for (int p = 0; p < 4; ++p) {
            int kk = lk + p * 4;
            int g = col0 + lc;
            float vr = 0.f, vi = 0.f;
            if (g < ncols) {
                int t0 = g >> 3;
                int rc = (j0 - t0) * 256 + t0 * 8 + (g & 7);   // a*256 + t0*8 + b
                vr = Xr[(long)(k0 + kk) * 8192 + rc];
                vi = Xi[(long)(k0 + kk) * 8192 + rc];
            }
            Bs_r[kk][lc] = vr; Bs_i[kk][lc] = vi;
        }
        __syncthreads();
#pragma unroll
        for (int kk = 0; kk < 16; ++kk) {
            float4 a4r = *(const float4*)(&As_r[kk][ty * 4]);
            float4 a4i = *(const float4*)(&As_i[kk][ty * 4]);
            float4 b4r = *(const float4*)(&Bs_r[kk][tx * 4]);
            float4 b4i = *(const float4*)(&Bs_i[kk][tx * 4]);
            float ar_[4] = {a4r.x, a4r.y, a4r.z, a4r.w};
            float ai_[4] = {a4i.x, a4i.y, a4i.z, a4i.w};
            float br_[4] = {b4r.x, b4r.y, b4r.z, b4r.w};
            float bi_[4] = {b4i.x, b4i.y, b4i.z, b4i.w};
#pragma unroll
            for (int i = 0; i < 4; ++i)
#pragma unroll
                for (int j = 0; j < 4; ++j) {
                    accr[i][j] = fmaf(ar_[i], br_[j], accr[i][j]);
                    accr[i][j] = fmaf(-ai_[i], bi_[j], accr[i][j]);
                    acci[i][j] = fmaf(ar_[i], bi_[j], acci[i][j]);
                    acci[i][j] = fmaf(ai_[i], br_[j], acci[i][j]);
                }
        }
        __syncthreads();
    }
    // epilogue: weight |A|^2 and reduce per (k, b); all cols here share t_out = j0 + c
#pragma unroll
    for (int i = 0; i < 4; ++i)
#pragma unroll
        for (int j = 0; j < 4; ++j) {
            int g = col0 + tx * 4 + j;
            if (g < ncols) {
                int t0 = g >> 3;
                float w = wt_s[j0 - t0 + c];                  // (1-lam)^(a+c)
                float v = w * (accr[i][j] * accr[i][j] + acci[i][j] * acci[i][j]);
                atomicAdd(&part[ty * 4 + i][g & 7], v);
            }
        }
    __syncthreads();
    const int tout = j0 + c;
    for (int e = tid; e < 512; e += 256) {
        int kl = e >> 3, b = e & 7;
        float v = part[kl][b];
        if (v != 0.f) atomicAdd(&pacc[((tout * 8 + b) << 8) + row0 + kl], v);
    }
}

// ---------------- MLP + log_softmax ----------------
__global__ __launch_bounds__(64) void k_mlp(
    const float* __restrict__ W1, const float* __restrict__ b1,
    const float* __restrict__ W2, const float* __restrict__ b2,
    const float* __restrict__ ws, float* __restrict__ out)
{
    const int t = blockIdx.x >> 3, b = blockIdx.x & 7;
    const int tid = threadIdx.x;
    __shared__ float pp[256], hh[64], oo[6];
    float ft = ws[OFF_COEF + 8 + t], s2 = ws[OFF_COEF + 1];
    const float* pacc = ws + OFF_PACC + ((t * 8 + b) << 8);
    for (int k = tid; k < 256; k += 64) pp[k] = ft + s2 * pacc[k];
    __syncthreads();
    float acc = b1[tid];
    for (int k = 0; k < 256; ++k) acc = fmaf(pp[k], W1[k * 64 + tid], acc);
    hh[tid] = fmaxf(acc, 0.f);
    __syncthreads();
    if (tid < 6) {
        float a = b2[tid];
        for (int k = 0; k < 64; ++k) a = fmaf(hh[k], W2[k * 6 + tid], a);
        oo[tid] = tanhf(a);
    }
    __syncthreads();
    if (tid == 0) {
        float m = oo[0];
        for (int c2 = 1; c2 < 6; ++c2) m = fmaxf(m, oo[c2]);
        float s = 0.f;
        for (int c2 = 0; c2 < 6; ++c2) s += expf(oo[c2] - m);
        float lse = m + logf(s);
        for (int c2 = 0; c2 < 6; ++c2) out[((long)b * 32 + t) * 6 + c2] = oo[c2] - lse;
    }
}

extern "C" void kernel_launch(void* const* d_in, const int* in_sizes, int n_in,
                              void* d_out, int out_size, void* d_ws, size_t ws_size,
                              hipStream_t stream)
{
    const float* xt  = (const float*)d_in[0];
    const float* xa  = (const float*)d_in[1];
    const float* xv  = (const float*)d_in[2];
    const float* sm  = (const float*)d_in[3];
    const float* Wt  = (const float*)d_in[4];
    const float* bt  = (const float*)d_in[5];
    const float* Wa  = (const float*)d_in[6];
    const float* ba  = (const float*)d_in[7];
    const float* Wv  = (const float*)d_in[8];
    const float* bv  = (const float*)d_in[9];
    const float* Pt  = (const float*)d_in[10];
    const float* Pa  = (const float*)d_in[11];
    const float* Pv  = (const float*)d_in[12];
    const float* Uxr = (const float*)d_in[13];
    const float* Uxi = (const float*)d_in[14];
    const float* Uhr = (const float*)d_in[15];
    const float* Uhi = (const float*)d_in[16];
    const float* Lam = (const float*)d_in[17];
    const float* Kr  = (const float*)d_in[18];
    const float* Ki  = (const float*)d_in[19];
    const float* W1  = (const float*)d_in[20];
    const float* b1  = (const float*)d_in[21];
    const float* W2  = (const float*)d_in[22];
    const float* b2  = (const float*)d_in[23];
    float* ws  = (float*)d_ws;
    float* out = (float*)d_out;

    float* PSIr = ws + OFF_PSI_R; float* PSIi = ws + OFF_PSI_I;
    float* P1r = ws + OFF_P_R;            float* P1i = ws + OFF_P_I;
    float* P2r = P1r + 65536;             float* P2i = P1i + 65536;
    float* P3r = P2r + 65536;             float* P3i = P2i + 65536;
    float* P4r = P3r + 65536;             float* P4i = P3i + 65536;
    float* PHr = ws + OFF_PHI_R;          float* PHi = ws + OFF_PHI_I;
    float* XIr = ws + OFF_XI_R;           float* XIi = ws + OFF_XI_I;
    float* Hr  = ws + OFF_H_R;            float* Hi  = ws + OFF_H_I;

    hipMemsetAsync(ws + OFF_PACC, 0, 65536 * sizeof(float), stream);
    k_coef<<<1, 64, 0, stream>>>(Lam, ws);
    k_norm<<<256, 256, 0, stream>>>(Kr, Ki, ws);
    k_psi<<<256, 256, 0, stream>>>(xt, xa, xv, sm, Wt, bt, Wa, ba, Wv, bv, Pt, Pa, Pv, ws);

    dim3 blk(256);
    // Phi_0 = Ux * Psi   (into Phi cols [0,256), ldC = 8192)
    k_cgemm<<<dim3(4, 4, 1), blk, 0, stream>>>(Uxr, Uxi, PSIr, PSIi, PHr, PHi, 256, 256, 8192, 0, 0, 0);
    // P powers: P1=Uh^2, P2=Uh^4, P3=Uh^8, P4=Uh^16
    k_cgemm<<<dim3(4, 4, 1), blk, 0, stream>>>(Uhr, Uhi, Uhr, Uhi, P1r, P1i, 256, 256, 256, 0, 0, 0);
    k_cgemm<<<dim3(4, 4, 1), blk, 0, stream>>>(P1r, P1i, P1r, P1i, P2r, P2i, 256, 256, 256, 0, 0, 0);
    k_cgemm<<<dim3(4, 4, 1), blk, 0, stream>>>(P2r, P2i, P2r, P2i, P3r, P3i, 256, 256, 256, 0, 0, 0);
    k_cgemm<<<dim3(4, 4, 1), blk, 0, stream>>>(P3r, P3i, P3r, P3i, P4r, P4i, 256, 256, 256, 0, 0, 0);
    // Phi doubling over a: Phi[a+2^j] = Uh^{2^j} * Phi[a]
    k_cgemm<<<dim3(4,  4, 1), blk, 0, stream>>>(Uhr, Uhi, PHr, PHi, PHr + 256,  PHi + 256,  256,  8192, 8192, 0, 0, 0);
    k_cgemm<<<dim3(8,  4, 1), blk, 0, stream>>>(P1r, P1i, PHr, PHi, PHr + 512,  PHi + 512,  512,  8192, 8192, 0, 0, 0);
    k_cgemm<<<dim3(16, 4, 1), blk, 0, stream>>>(P2r, P2i, PHr, PHi, PHr + 1024, PHi + 1024, 1024, 8192, 8192, 0, 0, 0);
    k_cgemm<<<dim3(32, 4, 1), blk, 0, stream>>>(P3r, P3i, PHr, PHi, PHr + 2048, PHi + 2048, 2048, 8192, 8192, 0, 0, 0);
    k_cgemm<<<dim3(64, 4, 1), blk, 0, stream>>>(P4r, P4i, PHr, PHi, PHr + 4096, PHi + 4096, 4096, 8192, 8192, 0, 0, 0);
    // Xi = Ux * Phi (all 8192 cols)
    k_cgemm<<<dim3(128, 4, 1), blk, 0, stream>>>(Uxr, Uxi, PHr, PHi, XIr, XIi, 8192, 8192, 8192, 0, 0, 0);
    // H chain: H_{c+2^j} = H_c * Uh^{2^j}  (batched over existing c)
    k_cgemm<<<dim3(4, 4, 1),  blk, 0, stream>>>(Hr, Hi, Uhr, Uhi, Hr + 65536,      Hi + 65536,      256, 256, 256, 65536, 0, 65536);
    k_cgemm<<<dim3(4, 4, 2),  blk, 0, stream>>>(Hr, Hi, P1r, P1i, Hr + 2 * 65536,  Hi + 2 * 65536,  256, 256, 256, 65536, 0, 65536);
    k_cgemm<<<dim3(4, 4, 4),  blk, 0, stream>>>(Hr, Hi, P2r, P2i, Hr + 4 * 65536,  Hi + 4 * 65536,  256, 256, 256, 65536, 0, 65536);
    k_cgemm<<<dim3(4, 4, 8),  blk, 0, stream>>>(Hr, Hi, P3r, P3i, Hr + 8 * 65536,  Hi + 8 * 65536,  256, 256, 256, 65536, 0, 65536);
    k_cgemm<<<dim3(4, 4, 16), blk, 0, stream>>>(Hr, Hi, P4r, P4i, Hr + 16 * 65536, Hi + 16 * 65536, 256, 256, 256, 65536, 0, 65536);
    // fused measurement into probs accumulator
    k_measure<<<dim3(16, 32, 32), blk, 0, stream>>>(ws);
    // MLP head + log_softmax
    k_mlp<<<256, 64, 0, stream>>>(W1, b1, W2, b2, ws, out);
}

// Round 2
// 633.197 us; speedup vs baseline: 3.1569x; 3.1569x over previous
//
#include <hip/hip_runtime.h>

#define TT 32
#define BETA_ 0.8f

typedef __bf16 bf16_t;
typedef bf16_t bf16x8 __attribute__((ext_vector_type(8)));
typedef float f32x4 __attribute__((ext_vector_type(4)));

// ---------------- workspace layout ----------------
// f32 region: [0..256) coefs, [256..65792) PACC
#define PACC_F 256
#define BF_BASE_B 263168              // byte offset of bf16 region (16B aligned)
// bf16-element offsets (plane-major storage; plane order: 0 rH, 1 iH, 2 rL, 3 iL, 4 niH, 5 niL)
#define O_SUX   0L                    // 6 x 65536
#define O_SUH   (O_SUX  + 393216L)
#define O_SUHT  (O_SUH  + 393216L)
#define O_SP    (O_SUHT + 393216L)    // 4 mats x 6 x 65536
#define O_SPT   (O_SP   + 4*393216L)
#define O_SPSI  (O_SPT  + 4*393216L)
#define O_SPHI  (O_SPSI + 393216L)    // 6 x 2097152  (8192 rows x 256)
#define O_SXI   (O_SPHI + 6*2097152L) // 2 x 2097152
#define O_SH    (O_SXI  + 2*2097152L) // 6 x 2097152  (32 c x 65536)

#define LDSPAD 40

__device__ inline f32x4 MF(bf16x8 a, bf16x8 b, f32x4 c) {
    return __builtin_amdgcn_mfma_f32_16x16x32_bf16(a, b, c, 0, 0, 0);
}

__device__ inline void split6(float vr, float vi, bf16_t* o, long ps, long idx, int mask) {
    bf16_t rh = (bf16_t)vr; o[idx] = rh;
    bf16_t ih = (bf16_t)vi; o[ps + idx] = ih;
    if (mask & 1) {
        o[2*ps + idx] = (bf16_t)(vr - (float)rh);
        o[3*ps + idx] = (bf16_t)(vi - (float)ih);
    }
    if (mask & 2) {
        float nv = -vi; bf16_t nh = (bf16_t)nv;
        o[4*ps + idx] = nh;
        o[5*ps + idx] = (bf16_t)(nv - (float)nh);
    }
}

// ---------------- scalar coefficients ----------------
__global__ void k_coef(const float* __restrict__ Lam, float* __restrict__ WF)
{
    if (threadIdx.x != 0) return;
    float lam = 1.f / (1.f + expf(-Lam[0]));
    float oml = 1.f - lam;
    WF[0] = lam;
    WF[1] = BETA_ * BETA_ * lam * lam;
    float w = 1.f;
    for (int n = 0; n < 64; ++n) { WF[64 + n] = w; w *= oml; }
    float a1 = 1.f / 256.f, a2 = 1.f / 256.f;
    for (int t = 0; t < 32; ++t) {
        a1 = oml * a1;
        float y1 = BETA_ * a1 + (1.f - BETA_) / 256.f;
        a2 = lam * y1 + oml * a2;
        WF[8 + t] = BETA_ * a2 + (1.f - BETA_) / 256.f;
    }
}

// ---------------- split f32 matrix -> 6 bf16 planes (+ optional transposed copy) ----------------
__global__ __launch_bounds__(256) void k_split_u(const float* __restrict__ Ur,
                                                 const float* __restrict__ Ui,
                                                 bf16_t* __restrict__ N,
                                                 bf16_t* __restrict__ T)
{
    int i = blockIdx.x, j = threadIdx.x;
    float vr = Ur[i * 256 + j], vi = Ui[i * 256 + j];
    split6(vr, vi, N, 65536L, (long)i * 256 + j, 3);
    if (T) split6(vr, vi, T, 65536L, (long)j * 256 + i, 3);
}

// ---------------- H_0 = conj(normalized K rows) ----------------
__global__ __launch_bounds__(256) void k_norm(const float* __restrict__ Kr,
                                              const float* __restrict__ Ki,
                                              bf16_t* __restrict__ SH)
{
    int k = blockIdx.x, i = threadIdx.x;
    float vr = Kr[k * 256 + i], vi = Ki[k * 256 + i];
    __shared__ float red[256];
    red[i] = vr * vr + vi * vi;
    __syncthreads();
    for (int s = 128; s > 0; s >>= 1) { if (i < s) red[i] += red[i + s]; __syncthreads(); }
    float inv = 1.f / sqrtf(red[0]);
    split6(vr * inv, -vi * inv, SH, 2097152L, (long)k * 256 + i, 3);
}

// ---------------- pure states psi (transposed [col][256]), split-written ----------------
__global__ __launch_bounds__(256) void k_psi(
    const float* __restrict__ xt, const float* __restrict__ xa, const float* __restrict__ xv,
    const float* __restrict__ sm,
    const float* __restrict__ Wt, const float* __restrict__ bt,
    const float* __restrict__ Wa, const float* __restrict__ ba,
    const float* __restrict__ Wv, const float* __restrict__ bv,
    const float* __restrict__ Pt, const float* __restrict__ Pa, const float* __restrict__ Pv,
    bf16_t* __restrict__ SPsi)
{
    const int colS = blockIdx.x;            // t0*8 + b
    const int t0 = colS >> 3, b = colS & 7;
    const long bt_ = (long)b * TT + t0;
    const int tid = threadIdx.x;
    __shared__ float rt[4], ra[8], rv[8], inv3[3];
    if (tid < 4) {
        float acc = bt[tid];
        const float* x = xt + bt_ * 300;
        for (int q = 0; q < 300; ++q) acc = fmaf(x[q], Wt[q * 4 + tid], acc);
        rt[tid] = fmaxf(acc, 0.f);
    } else if (tid < 12) {
        int u = tid - 4;
        float acc = ba[u];
        const float* x = xa + bt_ * 74;
        for (int q = 0; q < 74; ++q) acc = fmaf(x[q], Wa[q * 8 + u], acc);
        ra[u] = fmaxf(acc, 0.f);
    } else if (tid < 20) {
        int u = tid - 12;
        float acc = bv[u];
        const float* x = xv + bt_ * 35;
        for (int q = 0; q < 35; ++q) acc = fmaf(x[q], Wv[q * 8 + u], acc);
        rv[u] = fmaxf(acc, 0.f);
    }
    __syncthreads();
    if (tid == 0) {
        float s = 0.f; for (int u = 0; u < 4; ++u) s += rt[u] * rt[u];
        inv3[0] = 1.f / fmaxf(sqrtf(s), 1e-12f);
        s = 0.f; for (int u = 0; u < 8; ++u) s += ra[u] * ra[u];
        inv3[1] = 1.f / fmaxf(sqrtf(s), 1e-12f);
        s = 0.f; for (int u = 0; u < 8; ++u) s += rv[u] * rv[u];
        inv3[2] = 1.f / fmaxf(sqrtf(s), 1e-12f);
    }
    __syncthreads();
    float s0 = sm[bt_ * 2], s1 = sm[bt_ * 2 + 1];
    int spk = (s1 > s0) ? 1 : 0;
    int d = tid;
    int ti = d >> 6, ai = (d >> 3) & 7, vi = d & 7;
    float amp = (rt[ti] * inv3[0]) * (ra[ai] * inv3[1]) * (rv[vi] * inv3[2]);
    float ph = Pt[spk * 4 + ti] + Pa[spk * 8 + ai] + Pv[spk * 8 + vi];
    split6(amp * cosf(ph), amp * sinf(ph), SPsi, 65536L, (long)colS * 256 + d, 3);
}

// ---------------- split-precision complex MFMA GEMM ----------------
// D[m][n] = sum_k A[m][k] * Bsrc[n][k]  (complex; A/B split hi/lo bf16; C split-written)
// All leading dims are 256. Grid: x = M/64, y = 4 (N=256), z = batch.
__global__ __launch_bounds__(256) void k_cgemm_mx(
    const bf16_t* __restrict__ A, long aPS,
    const bf16_t* __restrict__ B, long bPS,
    bf16_t* __restrict__ C, long cPS,
    long aS, long bS, long cS, int wmask)
{
    __shared__ __align__(16) bf16_t sA[6][64][LDSPAD];
    __shared__ __align__(16) bf16_t sB[4][64][LDSPAD];
    const long bz = blockIdx.z;
    A += bz * aS; B += bz * bS; C += bz * cS;
    const int m0 = blockIdx.x * 64, n0 = blockIdx.y * 64;
    const int tid = threadIdx.x;
    const int lane = tid & 63, w = tid >> 6;
    const int wm = w >> 1, wn = w & 1;
    const int fr = lane & 15, fg = lane >> 4;
    f32x4 accr[2][2] = {}; f32x4 acci[2][2] = {};
    for (int ks = 0; ks < 8; ++ks) {
        {
            int idx = tid;
#pragma unroll
            for (int rep = 0; rep < 6; ++rep, idx += 256) {   // A: 6 planes x 64 rows x 4 chunks
                int p = idx >> 8, rem = idx & 255;
                int r = rem >> 2, cch = rem & 3;
                uint4 v = *(const uint4*)(A + p * aPS + (long)(m0 + r) * 256 + ks * 32 + cch * 8);
                *(uint4*)(&sA[p][r][cch * 8]) = v;
            }
            idx = tid;
#pragma unroll
            for (int rep = 0; rep < 4; ++rep, idx += 256) {   // B: 4 planes x 64 rows x 4 chunks
                int p = idx >> 8, rem = idx & 255;
                int r = rem >> 2, cch = rem & 3;
                uint4 v = *(const uint4*)(B + p * bPS + (long)(n0 + r) * 256 + ks * 32 + cch * 8);
                *(uint4*)(&sB[p][r][cch * 8]) = v;
            }
        }
        __syncthreads();
        bf16x8 aF[2][6], bF[2][4];
#pragma unroll
        for (int fm = 0; fm < 2; ++fm) {
            int row = wm * 32 + fm * 16 + fr;
#pragma unroll
            for (int p = 0; p < 6; ++p) aF[fm][p] = *(const bf16x8*)(&sA[p][row][fg * 8]);
        }
#pragma unroll
        for (int fn = 0; fn < 2; ++fn) {
            int row = wn * 32 + fn * 16 + fr;
#pragma unroll
            for (int p = 0; p < 4; ++p) bF[fn][p] = *(const bf16x8*)(&sB[p][row][fg * 8]);
        }
#pragma unroll
        for (int fm = 0; fm < 2; ++fm)
#pragma unroll
            for (int fn = 0; fn < 2; ++fn) {
                f32x4 r = accr[fm][fn], im = acci[fm][fn];
                r  = MF(aF[fm][0], bF[fn][0], r );   // rH*rH
                r  = MF(aF[fm][0], bF[fn][2], r );   // rH*rL
                r  = MF(aF[fm][2], bF[fn][0], r );   // rL*rH
                r  = MF(aF[fm][4], bF[fn][1], r );   // niH*iH
                r  = MF(aF[fm][4], bF[fn][3], r );   // niH*iL
                r  = MF(aF[fm][5], bF[fn][1], r );   // niL*iH
                im = MF(aF[fm][0], bF[fn][1], im);   // rH*iH
                im = MF(aF[fm][0], bF[fn][3], im);   // rH*iL
                im = MF(aF[fm][2], bF[fn][1], im);   // rL*iH
                im = MF(aF[fm][1], bF[fn][0], im);   // iH*rH
                im = MF(aF[fm][1], bF[fn][2], im);   // iH*rL
                im = MF(aF[fm][3], bF[fn][0], im);   // iL*rH
                accr[fm][fn] = r; acci[fm][fn] = im;
            }
        __syncthreads();
    }
#pragma unroll
    for (int fm = 0; fm < 2; ++fm)
#pragma unroll
        for (int fn = 0; fn < 2; ++fn)
#pragma unroll
            for (int r4 = 0; r4 < 4; ++r4) {
                int m = m0 + wm * 32 + fm * 16 + fg * 4 + r4;
                int n = n0 + wn * 32 + fn * 16 + fr;
                split6(accr[fm][fn][r4], acci[fm][fn][r4], C, cPS, (long)m * 256 + n, wmask);
            }
}

// ---------------- fused measurement (hi-only bf16 MFMA + w*|.|^2 atomic reduce) ----------------
// grid: x = kblk(2)*4 + chunk(4), y = a (32), z = c (32)
__global__ __launch_bounds__(256) void k_measure_mx(void* wsv)
{
    float* WF = (float*)wsv;
    bf16_t* bf = (bf16_t*)((char*)wsv + BF_BASE_B);
    const int c = blockIdx.z, a = blockIdx.y;
    if (a + c > 31) return;
    const int kblk = blockIdx.x >> 2, chunk = blockIdx.x & 3;
    const int ncols = (32 - a - c) * 8;
    if (chunk * 64 >= ncols) return;
    const bf16_t* H = bf + O_SH + (long)c * 65536;
    const bf16_t* X = bf + O_SXI + (long)(a * 256 + chunk * 64) * 256;
    __shared__ __align__(16) bf16_t sA[3][128][LDSPAD];   // Hr, Hi, -Hi (hi planes 0,1,4)
    __shared__ __align__(16) bf16_t sB[2][64][LDSPAD];    // Xr, Xi (hi)
    const int tid = threadIdx.x;
    const int lane = tid & 63, w = tid >> 6;
    const int wm = w >> 1, wn = w & 1;
    const int fr = lane & 15, fg = lane >> 4;
    f32x4 accr[4][2] = {}; f32x4 acci[4][2] = {};
    for (int ks = 0; ks < 8; ++ks) {
        {
            int idx = tid;
#pragma unroll
            for (int rep = 0; rep < 6; ++rep, idx += 256) {   // A: 3 planes x 128 rows x 4 chunks
                int p = idx >> 9, rem = idx & 511;
                int r = rem >> 2, cch = rem & 3;
                int pl = (p == 2) ? 4 : p;
                uint4 v = *(const uint4*)(H + (long)pl * 2097152 + (long)(kblk * 128 + r) * 256 + ks * 32 + cch * 8);
                *(uint4*)(&sA[p][r][cch * 8]) = v;
            }
            idx = tid;
#pragma unroll
            for (int rep = 0; rep < 2; ++rep, idx += 256) {   // B: 2 planes x 64 rows x 4 chunks
                int p = idx >> 8, rem = idx & 255;
                int r = rem >> 2, cch = rem & 3;
                uint4 v = *(const uint4*)(X + (long)p * 2097152 + (long)r * 256 + ks * 32 + cch * 8);
                *(uint4*)(&sB[p][r][cch * 8]) = v;
            }
        }
        __syncthreads();
        bf16x8 aF[4][3], bF[2][2];
#pragma unroll
        for (int fm = 0; fm < 4; ++fm) {
            int row = wm * 64 + fm * 16 + fr;
#pragma unroll
            for (int p = 0; p < 3; ++p) aF[fm][p] = *(const bf16x8*)(&sA[p][row][fg * 8]);
        }
#pragma unroll
        for (int fn = 0; fn < 2; ++fn) {
            int row = wn * 32 + fn * 16 + fr;
#pragma unroll
            for (int p = 0; p < 2; ++p) bF[fn][p] = *(const bf16x8*)(&sB[p][row][fg * 8]);
        }
#pragma unroll
        for (int fm = 0; fm < 4; ++fm)
#pragma unroll
            for (int fn = 0; fn < 2; ++fn) {
                f32x4 r = accr[fm][fn], im = acci[fm][fn];
                r  = MF(aF[fm][0], bF[fn][0], r );   // Hr*Xr
                r  = MF(aF[fm][2], bF[fn][1], r );   // -Hi*Xi
                im = MF(aF[fm][0], bF[fn][1], im);   // Hr*Xi
                im = MF(aF[fm][1], bF[fn][0], im);   // Hi*Xr
                accr[fm][fn] = r; acci[fm][fn] = im;
            }
        __syncthreads();
    }
    const float wv = WF[64 + a + c];
    float* pacc = WF + PACC_F;
#pragma unroll
    for (int fm = 0; fm < 4; ++fm)
#pragma unroll
        for (int fn = 0; fn < 2; ++fn)
#pragma unroll
            for (int r4 = 0; r4 < 4; ++r4) {
                int k = kblk * 128 + wm * 64 + fm * 16 + fg * 4 + r4;
                int g = chunk * 64 + wn * 32 + fn * 16 + fr;
                int t = (g >> 3) + a + c;
                if (t < 32) {
                    float vr = accr[fm][fn][r4], vi = acci[fm][fn][r4];
                    atomicAdd(&pacc[((t * 8 + (g & 7)) << 8) + k], wv * (vr * vr + vi * vi));
                }
            }
}

// ---------------- MLP + log_softmax ----------------
__global__ __launch_bounds__(64) void k_mlp(
    const float* __restrict__ W1, const float* __restrict__ b1,
    const float* __restrict__ W2, const float* __restrict__ b2,
    const float* __restrict__ WF, float* __restrict__ out)
{
    const int t = blockIdx.x >> 3, b = blockIdx.x & 7;
    const int tid = threadIdx.x;
    __shared__ float pp[256], hh[64], oo[6];
    float ft = WF[8 + t], s2 = WF[1];
    const float* pacc = WF + PACC_F + ((t * 8 + b) << 8);
    for (int k = tid; k < 256; k += 64) pp[k] = ft + s2 * pacc[k];
    __syncthreads();
    float acc = b1[tid];
    for (int k = 0; k < 256; ++k) acc = fmaf(pp[k], W1[k * 64 + tid], acc);
    hh[tid] = fmaxf(acc, 0.f);
    __syncthreads();
    if (tid < 6) {
        float a = b2[tid];
        for (int k = 0; k < 64; ++k) a = fmaf(hh[k], W2[k * 6 + tid], a);
        oo[tid] = tanhf(a);
    }
    __syncthreads();
    if (tid == 0) {
        float m = oo[0];
        for (int c2 = 1; c2 < 6; ++c2) m = fmaxf(m, oo[c2]);
        float s = 0.f;
        for (int c2 = 0; c2 < 6; ++c2) s += expf(oo[c2] - m);
        float lse = m + logf(s);
        for (int c2 = 0; c2 < 6; ++c2) out[((long)b * 32 + t) * 6 + c2] = oo[c2] - lse;
    }
}

extern "C" void kernel_launch(void* const* d_in, const int* in_sizes, int n_in,
                              void* d_out, int out_size, void* d_ws, size_t ws_size,
                              hipStream_t stream)
{
    const float* xt  = (const float*)d_in[0];
    const float* xa  = (const float*)d_in[1];
    const float* xv  = (const float*)d_in[2];
    const float* sm  = (const float*)d_in[3];
    const float* Wt  = (const float*)d_in[4];
    const float* bt  = (const float*)d_in[5];
    const float* Wa  = (const float*)d_in[6];
    const float* ba  = (const float*)d_in[7];
    const float* Wv  = (const float*)d_in[8];
    const float* bv  = (const float*)d_in[9];
    const float* Pt  = (const float*)d_in[10];
    const float* Pa  = (const float*)d_in[11];
    const float* Pv  = (const float*)d_in[12];
    const float* Uxr = (const float*)d_in[13];
    const float* Uxi = (const float*)d_in[14];
    const float* Uhr = (const float*)d_in[15];
    const float* Uhi = (const float*)d_in[16];
    const float* Lam = (const float*)d_in[17];
    const float* Kr  = (const float*)d_in[18];
    const float* Ki  = (const float*)d_in[19];
    const float* W1  = (const float*)d_in[20];
    const float* b1  = (const float*)d_in[21];
    const float* W2  = (const float*)d_in[22];
    const float* b2  = (const float*)d_in[23];
    float* WF  = (float*)d_ws;
    float* out = (float*)d_out;
    bf16_t* bf = (bf16_t*)((char*)d_ws + BF_BASE_B);

    bf16_t* SUx  = bf + O_SUX;
    bf16_t* SUh  = bf + O_SUH;
    bf16_t* SUhT = bf + O_SUHT;
    bf16_t* SP1  = bf + O_SP;              bf16_t* SPT1 = bf + O_SPT;
    bf16_t* SP2  = SP1 + 393216;           bf16_t* SPT2 = SPT1 + 393216;
    bf16_t* SP3  = SP2 + 393216;           bf16_t* SPT3 = SPT2 + 393216;
    bf16_t* SP4  = SP3 + 393216;           bf16_t* SPT4 = SPT3 + 393216;
    bf16_t* SPsi = bf + O_SPSI;
    bf16_t* SPhi = bf + O_SPHI;
    bf16_t* SXi  = bf + O_SXI;
    bf16_t* SH   = bf + O_SH;

    const long PS_S = 65536, PS_L = 2097152;

    hipMemsetAsync(WF + PACC_F, 0, 65536 * sizeof(float), stream);
    k_coef<<<1, 64, 0, stream>>>(Lam, WF);
    k_split_u<<<256, 256, 0, stream>>>(Uxr, Uxi, SUx, nullptr);
    k_split_u<<<256, 256, 0, stream>>>(Uhr, Uhi, SUh, SUhT);
    k_psi<<<256, 256, 0, stream>>>(xt, xa, xv, sm, Wt, bt, Wa, ba, Wv, bv, Pt, Pa, Pv, SPsi);
    k_norm<<<256, 256, 0, stream>>>(Kr, Ki, SH);

    dim3 blk(256);
    // P powers (natural + transposed): P1=Uh^2 ... P4=Uh^16
    k_cgemm_mx<<<dim3(4, 4, 1), blk, 0, stream>>>(SUh,  PS_S, SUhT, PS_S, SP1,  PS_S, 0, 0, 0, 3);
    k_cgemm_mx<<<dim3(4, 4, 1), blk, 0, stream>>>(SUhT, PS_S, SUh,  PS_S, SPT1, PS_S, 0, 0, 0, 3);
    k_cgemm_mx<<<dim3(4, 4, 1), blk, 0, stream>>>(SP1,  PS_S, SPT1, PS_S, SP2,  PS_S, 0, 0, 0, 3);
    k_cgemm_mx<<<dim3(4, 4, 1), blk, 0, stream>>>(SPT1, PS_S, SP1,  PS_S, SPT2, PS_S, 0, 0, 0, 3);
    k_cgemm_mx<<<dim3(4, 4, 1), blk, 0, stream>>>(SP2,  PS_S, SPT2, PS_S, SP3,  PS_S, 0, 0, 0, 3);
    k_cgemm_mx<<<dim3(4, 4, 1), blk, 0, stream>>>(SPT2, PS_S, SP2,  PS_S, SPT3, PS_S, 0, 0, 0, 3);
    k_cgemm_mx<<<dim3(4, 4, 1), blk, 0, stream>>>(SP3,  PS_S, SPT3, PS_S, SP4,  PS_S, 0, 0, 0, 3);
    k_cgemm_mx<<<dim3(4, 4, 1), blk, 0, stream>>>(SPT3, PS_S, SP3,  PS_S, SPT4, PS_S, 0, 0, 0, 3);
    // Phi_0 = Ux * Psi  (rows [0,256))
    k_cgemm_mx<<<dim3(4, 4, 1), blk, 0, stream>>>(SPsi, PS_S, SUx, PS_S, SPhi, PS_L, 0, 0, 0, 3);
    // Phi doubling over a
    k_cgemm_mx<<<dim3(4,  4, 1), blk, 0, stream>>>(SPhi, PS_L, SUh, PS_S, SPhi + 256L*256,  PS_L, 0, 0, 0, 3);
    k_cgemm_mx<<<dim3(8,  4, 1), blk, 0, stream>>>(SPhi, PS_L, SP1, PS_S, SPhi + 512L*256,  PS_L, 0, 0, 0, 3);
    k_cgemm_mx<<<dim3(16, 4, 1), blk, 0, stream>>>(SPhi, PS_L, SP2, PS_S, SPhi + 1024L*256, PS_L, 0, 0, 0, 3);
    k_cgemm_mx<<<dim3(32, 4, 1), blk, 0, stream>>>(SPhi, PS_L, SP3, PS_S, SPhi + 2048L*256, PS_L, 0, 0, 0, 3);
    k_cgemm_mx<<<dim3(64, 4, 1), blk, 0, stream>>>(SPhi, PS_L, SP4, PS_S, SPhi + 4096L*256, PS_L, 0, 0, 0, 3);
    // Xi = Ux * Phi (hi planes only)
    k_cgemm_mx<<<dim3(128, 4, 1), blk, 0, stream>>>(SPhi, PS_L, SUx, PS_S, SXi, PS_L, 0, 0, 0, 0);
    // H chain (batched doubling over c)
    k_cgemm_mx<<<dim3(4, 4, 1),  blk, 0, stream>>>(SH, PS_L, SUhT, PS_S, SH + 1L*65536,  PS_L, 65536, 0, 65536, 3);
    k_cgemm_mx<<<dim3(4, 4, 2),  blk, 0, stream>>>(SH, PS_L, SPT1, PS_S, SH + 2L*65536,  PS_L, 65536, 0, 65536, 3);
    k_cgemm_mx<<<dim3(4, 4, 4),  blk, 0, stream>>>(SH, PS_L, SPT2, PS_S, SH + 4L*65536,  PS_L, 65536, 0, 65536, 3);
    k_cgemm_mx<<<dim3(4, 4, 8),  blk, 0, stream>>>(SH, PS_L, SPT3, PS_S, SH + 8L*65536,  PS_L, 65536, 0, 65536, 3);
    k_cgemm_mx<<<dim3(4, 4, 16), blk, 0, stream>>>(SH, PS_L, SPT4, PS_S, SH + 16L*65536, PS_L, 65536, 0, 65536, 3);
    // fused measurement
    k_measure_mx<<<dim3(8, 32, 32), blk, 0, stream>>>(d_ws);
    // MLP head + log_softmax
    k_mlp<<<256, 64, 0, stream>>>(W1, b1, W2, b2, WF, out);
}

// Round 3
// 458.756 us; speedup vs baseline: 4.3574x; 1.3802x over previous
//
#include <hip/hip_runtime.h>

#define TT 32
#define BETA_ 0.8f

typedef __bf16 bf16_t;
typedef bf16_t bf16x8 __attribute__((ext_vector_type(8)));
typedef float f32x4 __attribute__((ext_vector_type(4)));

// ---------------- workspace layout ----------------
// f32 region: [0..256) coefs, [256..65792) PACC
#define PACC_F 256
#define BF_BASE_B 263168L             // byte offset of bf16 region (16B aligned)
// bf16 region = array of "units". Units 0..75 are 6-plane 256x256 split matrices
// (plane order: 0 rH, 1 iH, 2 rL, 3 iL, 4 niH, 5 niL), unit size 393216 elems.
// Units: 0 Ux, 1 Uh, 2 UhT, 3 Psi, 4..11 {P1,PT1,P2,PT2,P3,PT3,P4,PT4},
//        12..43 Phi[a], 44..75 H[c].
// Then Xi region: 32 units of 2 planes (131072 elems each) at XIB_E.
#define US 393216L
#define XU 131072L
#define XIB_E (76L * US)

#define LDSPAD 40

__device__ inline f32x4 MF(bf16x8 a, bf16x8 b, f32x4 c) {
    return __builtin_amdgcn_mfma_f32_16x16x32_bf16(a, b, c, 0, 0, 0);
}

__device__ inline void split6(float vr, float vi, bf16_t* o, long ps, long idx, int mask) {
    bf16_t rh = (bf16_t)vr; o[idx] = rh;
    bf16_t ih = (bf16_t)vi; o[ps + idx] = ih;
    if (mask & 1) {
        o[2*ps + idx] = (bf16_t)(vr - (float)rh);
        o[3*ps + idx] = (bf16_t)(vi - (float)ih);
    }
    if (mask & 2) {
        float nv = -vi; bf16_t nh = (bf16_t)nv;
        o[4*ps + idx] = nh;
        o[5*ps + idx] = (bf16_t)(nv - (float)nh);
    }
}

// ---------------- fused prep: coef + split U + psi + norm ----------------
__global__ __launch_bounds__(256) void k_prep(
    const float* __restrict__ xt, const float* __restrict__ xa, const float* __restrict__ xv,
    const float* __restrict__ sm,
    const float* __restrict__ Wt, const float* __restrict__ bt,
    const float* __restrict__ Wa, const float* __restrict__ ba,
    const float* __restrict__ Wv, const float* __restrict__ bv,
    const float* __restrict__ Pt, const float* __restrict__ Pa, const float* __restrict__ Pv,
    const float* __restrict__ Uxr, const float* __restrict__ Uxi,
    const float* __restrict__ Uhr, const float* __restrict__ Uhi,
    const float* __restrict__ Lam, const float* __restrict__ Kr, const float* __restrict__ Ki,
    void* wsv)
{
    float* WF = (float*)wsv;
    bf16_t* bf = (bf16_t*)((char*)wsv + BF_BASE_B);
    const int blk = blockIdx.x, tid = threadIdx.x;
    __shared__ float red[256];
    __shared__ float rt[4], ra[8], rv[8], inv3[3];

    if (blk == 0) {
        if (tid != 0) return;
        float lam = 1.f / (1.f + expf(-Lam[0]));
        float oml = 1.f - lam;
        WF[0] = lam;
        WF[1] = BETA_ * BETA_ * lam * lam;
        float w = 1.f;
        for (int n = 0; n < 64; ++n) { WF[64 + n] = w; w *= oml; }
        float a1 = 1.f / 256.f, a2 = 1.f / 256.f;
        for (int t = 0; t < 32; ++t) {
            a1 = oml * a1;
            float y1 = BETA_ * a1 + (1.f - BETA_) / 256.f;
            a2 = lam * y1 + oml * a2;
            WF[8 + t] = BETA_ * a2 + (1.f - BETA_) / 256.f;
        }
        return;
    }
    if (blk < 513) {                       // split Ux (1..256) / Uh+UhT (257..512)
        int i = (blk - 1) & 255, j = tid;
        if (blk < 257) {
            split6(Uxr[i * 256 + j], Uxi[i * 256 + j], bf + 0 * US, 65536L, (long)i * 256 + j, 3);
        } else {
            float vr = Uhr[i * 256 + j], vi = Uhi[i * 256 + j];
            split6(vr, vi, bf + 1 * US, 65536L, (long)i * 256 + j, 3);
            split6(vr, vi, bf + 2 * US, 65536L, (long)j * 256 + i, 3);
        }
        return;
    }
    if (blk < 769) {                       // psi, colS = t0*8+b
        const int colS = blk - 513;
        const int t0 = colS >> 3, b = colS & 7;
        const long bt_ = (long)b * TT + t0;
        if (tid < 4) {
            float acc = bt[tid];
            const float* x = xt + bt_ * 300;
            for (int q = 0; q < 300; ++q) acc = fmaf(x[q], Wt[q * 4 + tid], acc);
            rt[tid] = fmaxf(acc, 0.f);
        } else if (tid < 12) {
            int u = tid - 4;
            float acc = ba[u];
            const float* x = xa + bt_ * 74;
            for (int q = 0; q < 74; ++q) acc = fmaf(x[q], Wa[q * 8 + u], acc);
            ra[u] = fmaxf(acc, 0.f);
        } else if (tid < 20) {
            int u = tid - 12;
            float acc = bv[u];
            const float* x = xv + bt_ * 35;
            for (int q = 0; q < 35; ++q) acc = fmaf(x[q], Wv[q * 8 + u], acc);
            rv[u] = fmaxf(acc, 0.f);
        }
        __syncthreads();
        if (tid == 0) {
            float s = 0.f; for (int u = 0; u < 4; ++u) s += rt[u] * rt[u];
            inv3[0] = 1.f / fmaxf(sqrtf(s), 1e-12f);
            s = 0.f; for (int u = 0; u < 8; ++u) s += ra[u] * ra[u];
            inv3[1] = 1.f / fmaxf(sqrtf(s), 1e-12f);
            s = 0.f; for (int u = 0; u < 8; ++u) s += rv[u] * rv[u];
            inv3[2] = 1.f / fmaxf(sqrtf(s), 1e-12f);
        }
        __syncthreads();
        float s0 = sm[bt_ * 2], s1 = sm[bt_ * 2 + 1];
        int spk = (s1 > s0) ? 1 : 0;
        int d = tid;
        int ti = d >> 6, ai = (d >> 3) & 7, vi = d & 7;
        float amp = (rt[ti] * inv3[0]) * (ra[ai] * inv3[1]) * (rv[vi] * inv3[2]);
        float ph = Pt[spk * 4 + ti] + Pa[spk * 8 + ai] + Pv[spk * 8 + vi];
        split6(amp * cosf(ph), amp * sinf(ph), bf + 3 * US, 65536L, (long)colS * 256 + d, 3);
        return;
    }
    {                                      // norm: H0 = conj(normalized K rows) -> unit 44
        int k = blk - 769, i = tid;
        float vr = Kr[k * 256 + i], vi = Ki[k * 256 + i];
        red[i] = vr * vr + vi * vi;
        __syncthreads();
        for (int s = 128; s > 0; s >>= 1) { if (i < s) red[i] += red[i + s]; __syncthreads(); }
        float inv = 1.f / sqrtf(red[0]);
        split6(vr * inv, -vi * inv, bf + 44 * US, 65536L, (long)k * 256 + i, 3);
    }
}

// ---------------- generic batched split-complex MFMA GEMM ----------------
// C[m][n] = sum_k A[m][k] * B[n][k] (complex), all matrices 256x256 units.
struct Jobs {
    long aB[4], aS[4], bB[4], cB[4], cS[4];
    int wm[4], cnt[4];
};

__global__ __launch_bounds__(256) void k_gemm(void* wsv, Jobs J)
{
    bf16_t* bf = (bf16_t*)((char*)wsv + BF_BASE_B);
    int z = blockIdx.z, j = 0;
    while (z >= J.cnt[j]) { z -= J.cnt[j]; ++j; }
    const bf16_t* A = bf + J.aB[j] + (long)z * J.aS[j];
    const bf16_t* B = bf + J.bB[j];
    bf16_t*       C = bf + J.cB[j] + (long)z * J.cS[j];
    const int wmask = J.wm[j];

    __shared__ __align__(16) bf16_t sA[6][64][LDSPAD];
    __shared__ __align__(16) bf16_t sB[4][64][LDSPAD];
    const int m0 = blockIdx.x * 64, n0 = blockIdx.y * 64;
    const int tid = threadIdx.x;
    const int lane = tid & 63, w = tid >> 6;
    const int wm_ = w >> 1, wn = w & 1;
    const int fr = lane & 15, fg = lane >> 4;
    f32x4 accr[2][2] = {}; f32x4 acci[2][2] = {};
    for (int ks = 0; ks < 8; ++ks) {
        int idx = tid;
#pragma unroll
        for (int rep = 0; rep < 6; ++rep, idx += 256) {
            int p = idx >> 8, rem = idx & 255;
            int r = rem >> 2, cch = rem & 3;
            uint4 v = *(const uint4*)(A + (long)p * 65536 + (long)(m0 + r) * 256 + ks * 32 + cch * 8);
            *(uint4*)(&sA[p][r][cch * 8]) = v;
        }
        idx = tid;
#pragma unroll
        for (int rep = 0; rep < 4; ++rep, idx += 256) {
            int p = idx >> 8, rem = idx & 255;
            int r = rem >> 2, cch = rem & 3;
            uint4 v = *(const uint4*)(B + (long)p * 65536 + (long)(n0 + r) * 256 + ks * 32 + cch * 8);
            *(uint4*)(&sB[p][r][cch * 8]) = v;
        }
        __syncthreads();
        bf16x8 aF[2][6], bF[2][4];
#pragma unroll
        for (int fm = 0; fm < 2; ++fm) {
            int row = wm_ * 32 + fm * 16 + fr;
#pragma unroll
            for (int p = 0; p < 6; ++p) aF[fm][p] = *(const bf16x8*)(&sA[p][row][fg * 8]);
        }
#pragma unroll
        for (int fn = 0; fn < 2; ++fn) {
            int row = wn * 32 + fn * 16 + fr;
#pragma unroll
            for (int p = 0; p < 4; ++p) bF[fn][p] = *(const bf16x8*)(&sB[p][row][fg * 8]);
        }
#pragma unroll
        for (int fm = 0; fm < 2; ++fm)
#pragma unroll
            for (int fn = 0; fn < 2; ++fn) {
                f32x4 r = accr[fm][fn], im = acci[fm][fn];
                r  = MF(aF[fm][0], bF[fn][0], r );
                r  = MF(aF[fm][0], bF[fn][2], r );
                r  = MF(aF[fm][2], bF[fn][0], r );
                r  = MF(aF[fm][4], bF[fn][1], r );
                r  = MF(aF[fm][4], bF[fn][3], r );
                r  = MF(aF[fm][5], bF[fn][1], r );
                im = MF(aF[fm][0], bF[fn][1], im);
                im = MF(aF[fm][0], bF[fn][3], im);
                im = MF(aF[fm][2], bF[fn][1], im);
                im = MF(aF[fm][1], bF[fn][0], im);
                im = MF(aF[fm][1], bF[fn][2], im);
                im = MF(aF[fm][3], bF[fn][0], im);
                accr[fm][fn] = r; acci[fm][fn] = im;
            }
        __syncthreads();
    }
#pragma unroll
    for (int fm = 0; fm < 2; ++fm)
#pragma unroll
        for (int fn = 0; fn < 2; ++fn)
#pragma unroll
            for (int r4 = 0; r4 < 4; ++r4) {
                int m = m0 + wm_ * 32 + fm * 16 + fg * 4 + r4;
                int n = n0 + wn * 32 + fn * 16 + fr;
                split6(accr[fm][fn][r4], acci[fm][fn][r4], C, 65536L, (long)m * 256 + n, wmask);
            }
}

// ---------------- measurement v3: t-grouped, c-loop in block, register |.|^2 accum ----
// grid: x = kblk*4 + chunk (8), y = cb (4), z = t (32)
__global__ __launch_bounds__(256) void k_measure3(void* wsv)
{
    float* WF = (float*)wsv;
    bf16_t* bf = (bf16_t*)((char*)wsv + BF_BASE_B);
    const int t = blockIdx.z;
    const int cb = blockIdx.y;
    const int kblk = blockIdx.x >> 2, chunk = blockIdx.x & 3;
    const int cmax = t - 8 * chunk;              // inclusive upper bound on c
    const int clo = cb * 8;
    if (clo > cmax) return;
    const int chi = (clo + 8 < cmax + 1) ? clo + 8 : cmax + 1;

    __shared__ __align__(16) bf16_t sA[3][128][LDSPAD];   // Hr, Hi, -Hi
    __shared__ __align__(16) bf16_t sB[2][64][LDSPAD];    // Xi_r, Xi_i
    __shared__ float part[128][9];
    const int tid = threadIdx.x;
    const int lane = tid & 63, w = tid >> 6;
    const int wm = w >> 1, wn = w & 1;
    const int fr = lane & 15, fg = lane >> 4;
    float sacc[4][2][4] = {};

    for (int c = clo; c < chi; ++c) {
        const int j0 = t - c;
        const bf16_t* H = bf + (long)(44 + c) * US;
        f32x4 accr[4][2] = {}; f32x4 acci[4][2] = {};
        for (int ks = 0; ks < 8; ++ks) {
            int idx = tid;
#pragma unroll
            for (int rep = 0; rep < 6; ++rep, idx += 256) {   // A: 3 planes x 128 rows x 4 chunks
                int p = idx >> 9, rem = idx & 511;
                int r = rem >> 2, cch = rem & 3;
                int pl = (p == 2) ? 4 : p;
                uint4 v = *(const uint4*)(H + (long)pl * 65536 + (long)(kblk * 128 + r) * 256 + ks * 32 + cch * 8);
                *(uint4*)(&sA[p][r][cch * 8]) = v;
            }
            idx = tid;
#pragma unroll
            for (int rep = 0; rep < 2; ++rep, idx += 256) {   // B: gather Xi cols for this (t,c)
                int p = idx >> 8, rem = idx & 255;
                int r = rem >> 2, cch = rem & 3;
                int t0g = chunk * 8 + (r >> 3);
                uint4 v = {0u, 0u, 0u, 0u};
                if (t0g <= j0) {
                    long base = XIB_E + (long)(j0 - t0g) * XU + (long)p * 65536
                              + (long)(chunk * 64 + r) * 256 + ks * 32 + cch * 8;
                    v = *(const uint4*)(bf + base);
                }
                *(uint4*)(&sB[p][r][cch * 8]) = v;
            }
            __syncthreads();
            bf16x8 aF[4][3], bF[2][2];
#pragma unroll
            for (int fm = 0; fm < 4; ++fm) {
                int row = wm * 64 + fm * 16 + fr;
#pragma unroll
                for (int p = 0; p < 3; ++p) aF[fm][p] = *(const bf16x8*)(&sA[p][row][fg * 8]);
            }
#pragma unroll
            for (int fn = 0; fn < 2; ++fn) {
                int row = wn * 32 + fn * 16 + fr;
#pragma unroll
                for (int p = 0; p < 2; ++p) bF[fn][p] = *(const bf16x8*)(&sB[p][row][fg * 8]);
            }
#pragma unroll
            for (int fm = 0; fm < 4; ++fm)
#pragma unroll
                for (int fn = 0; fn < 2; ++fn) {
                    f32x4 r = accr[fm][fn], im = acci[fm][fn];
                    r  = MF(aF[fm][0], bF[fn][0], r );
                    r  = MF(aF[fm][2], bF[fn][1], r );
                    im = MF(aF[fm][0], bF[fn][1], im);
                    im = MF(aF[fm][1], bF[fn][0], im);
                    accr[fm][fn] = r; acci[fm][fn] = im;
                }
            __syncthreads();
        }
#pragma unroll
        for (int fm = 0; fm < 4; ++fm)
#pragma unroll
            for (int fn = 0; fn < 2; ++fn)
#pragma unroll
                for (int r4 = 0; r4 < 4; ++r4) {
                    float vr = accr[fm][fn][r4], vi = acci[fm][fn][r4];
                    sacc[fm][fn][r4] += vr * vr + vi * vi;
                }
    }
    // reduce: weight per column (depends only on t - t0), fold b-columns in LDS
    for (int e = tid; e < 128 * 9; e += 256) (&part[0][0])[e] = 0.f;
    __syncthreads();
#pragma unroll
    for (int fm = 0; fm < 4; ++fm)
#pragma unroll
        for (int fn = 0; fn < 2; ++fn)
#pragma unroll
            for (int r4 = 0; r4 < 4; ++r4) {
                int kl = wm * 64 + fm * 16 + fg * 4 + r4;
                int g = chunk * 64 + wn * 32 + fn * 16 + fr;
                int t0 = g >> 3;
                if (t0 <= t) atomicAdd(&part[kl][g & 7], WF[64 + (t - t0)] * sacc[fm][fn][r4]);
            }
    __syncthreads();
    float* pacc = WF + PACC_F;
    for (int e = tid; e < 1024; e += 256) {
        int kl = e >> 3, b = e & 7;
        float v = part[kl][b];
        if (v != 0.f) atomicAdd(&pacc[((t * 8 + b) << 8) + kblk * 128 + kl], v);
    }
}

// ---------------- MLP + log_softmax ----------------
__global__ __launch_bounds__(64) void k_mlp(
    const float* __restrict__ W1, const float* __restrict__ b1,
    const float* __restrict__ W2, const float* __restrict__ b2,
    const float* __restrict__ WF, float* __restrict__ out)
{
    const int t = blockIdx.x >> 3, b = blockIdx.x & 7;
    const int tid = threadIdx.x;
    __shared__ float pp[256], hh[64], oo[6];
    float ft = WF[8 + t], s2 = WF[1];
    const float* pacc = WF + PACC_F + ((t * 8 + b) << 8);
    for (int k = tid; k < 256; k += 64) pp[k] = ft + s2 * pacc[k];
    __syncthreads();
    float acc = b1[tid];
    for (int k = 0; k < 256; ++k) acc = fmaf(pp[k], W1[k * 64 + tid], acc);
    hh[tid] = fmaxf(acc, 0.f);
    __syncthreads();
    if (tid < 6) {
        float a = b2[tid];
        for (int k = 0; k < 64; ++k) a = fmaf(hh[k], W2[k * 6 + tid], a);
        oo[tid] = tanhf(a);
    }
    __syncthreads();
    if (tid == 0) {
        float m = oo[0];
        for (int c2 = 1; c2 < 6; ++c2) m = fmaxf(m, oo[c2]);
        float s = 0.f;
        for (int c2 = 0; c2 < 6; ++c2) s += expf(oo[c2] - m);
        float lse = m + logf(s);
        for (int c2 = 0; c2 < 6; ++c2) out[((long)b * 32 + t) * 6 + c2] = oo[c2] - lse;
    }
}

// ---------------- host ----------------
static inline void setJob(Jobs& J, int i, long aB, long aS, long bB, long cB, long cS,
                          int wm, int cnt)
{
    J.aB[i] = aB; J.aS[i] = aS; J.bB[i] = bB; J.cB[i] = cB; J.cS[i] = cS;
    J.wm[i] = wm; J.cnt[i] = cnt;
}

extern "C" void kernel_launch(void* const* d_in, const int* in_sizes, int n_in,
                              void* d_out, int out_size, void* d_ws, size_t ws_size,
                              hipStream_t stream)
{
    const float* xt  = (const float*)d_in[0];
    const float* xa  = (const float*)d_in[1];
    const float* xv  = (const float*)d_in[2];
    const float* sm  = (const float*)d_in[3];
    const float* Wt  = (const float*)d_in[4];
    const float* bt  = (const float*)d_in[5];
    const float* Wa  = (const float*)d_in[6];
    const float* ba  = (const float*)d_in[7];
    const float* Wv  = (const float*)d_in[8];
    const float* bv  = (const float*)d_in[9];
    const float* Pt  = (const float*)d_in[10];
    const float* Pa  = (const float*)d_in[11];
    const float* Pv  = (const float*)d_in[12];
    const float* Lam = (const float*)d_in[17];
    const float* Kr  = (const float*)d_in[18];
    const float* Ki  = (const float*)d_in[19];
    const float* W1  = (const float*)d_in[20];
    const float* b1  = (const float*)d_in[21];
    const float* W2  = (const float*)d_in[22];
    const float* b2  = (const float*)d_in[23];
    const float* Uxr = (const float*)d_in[13];
    const float* Uxi = (const float*)d_in[14];
    const float* Uhr = (const float*)d_in[15];
    const float* Uhi = (const float*)d_in[16];
    float* WF  = (float*)d_ws;
    float* out = (float*)d_out;

    hipMemsetAsync(WF + PACC_F, 0, 65536 * sizeof(float), stream);
    k_prep<<<1025, 256, 0, stream>>>(xt, xa, xv, sm, Wt, bt, Wa, ba, Wv, bv,
                                     Pt, Pa, Pv, Uxr, Uxi, Uhr, Uhi, Lam, Kr, Ki, d_ws);

    auto U = [](int u) { return (long)u * US; };
    dim3 blk(256);
    Jobs J;

    // S1: P1, PT1, Phi0 = Ux*Psi, H1 = H0*Uh
    setJob(J, 0, U(1), 0, U(2), U(4), 0, 3, 1);
    setJob(J, 1, U(2), 0, U(1), U(5), 0, 3, 1);
    setJob(J, 2, U(3), 0, U(0), U(12), 0, 3, 1);
    setJob(J, 3, U(44), 0, U(2), U(45), 0, 3, 1);
    k_gemm<<<dim3(4, 4, 4), blk, 0, stream>>>(d_ws, J);
    // S2: P2, PT2, Phi1 (B=Uh), H{2,3} (B=PT1)
    setJob(J, 0, U(4), 0, U(5), U(6), 0, 3, 1);
    setJob(J, 1, U(5), 0, U(4), U(7), 0, 3, 1);
    setJob(J, 2, U(12), 0, U(1), U(13), 0, 3, 1);
    setJob(J, 3, U(44), US, U(5), U(46), US, 3, 2);
    k_gemm<<<dim3(4, 4, 5), blk, 0, stream>>>(d_ws, J);
    // S3: P3, PT3, Phi{2,3} (B=P1), H{4..7} (B=PT2)
    setJob(J, 0, U(6), 0, U(7), U(8), 0, 3, 1);
    setJob(J, 1, U(7), 0, U(6), U(9), 0, 3, 1);
    setJob(J, 2, U(12), US, U(4), U(14), US, 3, 2);
    setJob(J, 3, U(44), US, U(7), U(48), US, 3, 4);
    k_gemm<<<dim3(4, 4, 8), blk, 0, stream>>>(d_ws, J);
    // S4: P4, PT4, Phi{4..7} (B=P2), H{8..15} (B=PT3)
    setJob(J, 0, U(8), 0, U(9), U(10), 0, 3, 1);
    setJob(J, 1, U(9), 0, U(8), U(11), 0, 3, 1);
    setJob(J, 2, U(12), US, U(6), U(16), US, 3, 4);
    setJob(J, 3, U(44), US, U(9), U(52), US, 3, 8);
    k_gemm<<<dim3(4, 4, 14), blk, 0, stream>>>(d_ws, J);
    // S5: Phi{8..15} (B=P3), H{16..31} (B=PT4)
    setJob(J, 0, U(12), US, U(8), U(20), US, 3, 8);
    setJob(J, 1, U(44), US, U(11), U(60), US, 3, 16);
    setJob(J, 2, 0, 0, 0, 0, 0, 0, 0);
    setJob(J, 3, 0, 0, 0, 0, 0, 0, 0);
    k_gemm<<<dim3(4, 4, 24), blk, 0, stream>>>(d_ws, J);
    // S6: Phi{16..31} (B=P4), Xi{0..15} = Ux*Phi{0..15} (hi-only)
    setJob(J, 0, U(12), US, U(10), U(28), US, 3, 16);
    setJob(J, 1, U(12), US, U(0), XIB_E, XU, 0, 16);
    k_gemm<<<dim3(4, 4, 32), blk, 0, stream>>>(d_ws, J);
    // S7: Xi{16..31}
    setJob(J, 0, U(28), US, U(0), XIB_E + 16 * XU, XU, 0, 16);
    setJob(J, 1, 0, 0, 0, 0, 0, 0, 0);
    k_gemm<<<dim3(4, 4, 16), blk, 0, stream>>>(d_ws, J);

    // measurement + head
    k_measure3<<<dim3(8, 4, 32), blk, 0, stream>>>(d_ws);
    k_mlp<<<256, 64, 0, stream>>>(W1, b1, W2, b2, WF, out);
}